// Round 3
// baseline (173.276 us; speedup 1.0000x reference)
//
#include <hip/hip_runtime.h>

// knn gather: b=2, s=8192 sources, t=4096 targets, e=128, NH=16
#define NHH 16
#define KSEL 18   // extract 18 by (sq,idx), re-rank by (sqrt,idx), keep 16

constexpr int BB = 2, SS = 8192, TT = 4096, EE = 128;
constexpr long long XBS_N = (long long)BB * TT * NHH * EE; // 16777216
constexpr long long IDX_N = (long long)BB * TT * NHH;      // 131072
constexpr long long CS_N  = (long long)BB * 2 * TT * NHH;  // 262144

// LDS swizzle: phys = s ^ ((s>>7)&31). Bijective per 128-block; makes both
// stride-128 (per-lane segment scan) and stride-1 (cooperative rescan of one
// owner's segment) accesses land 2 lanes/bank (free per m136).
__device__ __forceinline__ int swz(int s) { return s ^ ((s >> 7) & 31); }

__device__ __forceinline__ unsigned long long wmin64(unsigned long long k) {
#pragma unroll
  for (int off = 32; off > 0; off >>= 1) {
    unsigned long long o = __shfl_xor(k, off, 64);
    k = (o < k) ? o : k;
  }
  return k;
}

__global__ void __launch_bounds__(256) knn_select(
    const float* __restrict__ ct, const float* __restrict__ csrc,
    float* __restrict__ out, int idx64mode)
{
  __shared__ float lc1[SS];
  __shared__ float lc2[SS];

  const int b = blockIdx.x >> 8;            // 512 blocks: 0..255 -> batch 0
  const float* c1g = csrc + (size_t)b * 2 * SS;
  const float* c2g = c1g + SS;
  for (int k = threadIdx.x; k < SS; k += 256) {
    lc1[swz(k)] = c1g[k];
    lc2[swz(k)] = c2g[k];
  }
  __syncthreads();

  const int lane = threadIdx.x & 63;
  const int wave = threadIdx.x >> 6;
  const int tbase = ((blockIdx.x & 255) << 4) + (wave << 2); // 4 targets/wave

  float tx[4], ty[4];
#pragma unroll
  for (int j = 0; j < 4; ++j) {
    tx[j] = ct[(size_t)b * 2 * TT + tbase + j];
    ty[j] = ct[(size_t)b * 2 * TT + TT + tbase + j];
  }

  // ---- scan: each lane owns sources [128*lane, 128*lane+128), tracks min key
  unsigned long long cur[4] = {~0ull, ~0ull, ~0ull, ~0ull};
  const int base = lane << 7;
  const int xr = lane & 31;
#pragma unroll 4
  for (int i = 0; i < 128; ++i) {
    float sx = lc1[base + (i ^ xr)];
    float sy = lc2[base + (i ^ xr)];
    int s = base + i;
#pragma unroll
    for (int j = 0; j < 4; ++j) {
      // exact rounding to match XLA: separate rn mul/mul/add, no fma
      float dx = __fsub_rn(tx[j], sx);
      float dy = __fsub_rn(ty[j], sy);
      float sq = __fadd_rn(__fmul_rn(dx, dx), __fmul_rn(dy, dy));
      unsigned long long key =
          ((unsigned long long)__float_as_uint(sq) << 13) | (unsigned)s;
      if (key < cur[j]) cur[j] = key;
    }
  }

#pragma unroll
  for (int j = 0; j < 4; ++j) {
    unsigned long long curj = cur[j];
    unsigned long long ext = ~0ull;    // lane e holds e-th extracted key
    for (int e = 0; e < KSEL; ++e) {
      unsigned long long kmin = wmin64(curj);
      if (lane == e) ext = kmin;
      int widx  = (int)(kmin & 8191u);
      int owner = widx >> 7;
      // cooperative rescan of owner's 128-candidate segment for min key > kmin
      int ob = owner << 7;
      int oxr = owner & 31;
      unsigned long long r = ~0ull;
#pragma unroll
      for (int h = 0; h < 2; ++h) {
        int ii = lane + (h << 6);
        float sx = lc1[ob + (ii ^ oxr)];
        float sy = lc2[ob + (ii ^ oxr)];
        float dx = __fsub_rn(tx[j], sx);
        float dy = __fsub_rn(ty[j], sy);
        float sq = __fadd_rn(__fmul_rn(dx, dx), __fmul_rn(dy, dy));
        unsigned long long key =
            ((unsigned long long)__float_as_uint(sq) << 13) | (unsigned)(ob + ii);
        if (key > kmin && key < r) r = key;
      }
      unsigned long long nm = wmin64(r);
      if (lane == owner) curj = nm;
    }

    // ---- re-rank the 18 by (sqrt(sq), idx) to reproduce stable argsort on d
    unsigned long long nk = ~0ull;
    int sidx = 0;
    if (lane < KSEL) {
      float sq = __uint_as_float((unsigned)(ext >> 13));
      sidx = (int)(ext & 8191u);
      float d = __fsqrt_rn(sq);  // correctly-rounded f32 sqrt (matches XLA)
      nk = ((unsigned long long)__float_as_uint(d) << 13) | (unsigned)sidx;
    }
    int rank = 0;
#pragma unroll
    for (int e = 0; e < KSEL; ++e) {
      unsigned long long o = __shfl(nk, e, 64);
      if (o < nk) ++rank;
    }
    if (lane < KSEL && rank < NHH) {
      int t = tbase + j;
      long long ibase = XBS_N;
      if (idx64mode) {
        ((long long*)(out + ibase))[(size_t)b * TT * NHH + t * NHH + rank] =
            (long long)sidx;
      } else {
        out[ibase + (size_t)b * TT * NHH + t * NHH + rank] = (float)sidx;
      }
      long long cbase = XBS_N + (idx64mode ? 2 * IDX_N : IDX_N);
      float sx = lc1[swz(sidx)];
      float sy = lc2[swz(sidx)];
      out[cbase + (size_t)b * 2 * TT * NHH + t * NHH + rank] =
          __fsub_rn(tx[j], sx);
      out[cbase + (size_t)b * 2 * TT * NHH + TT * NHH + t * NHH + rank] =
          __fsub_rn(ty[j], sy);
    }
  }
}

__global__ void __launch_bounds__(256) gather_x(
    const float* __restrict__ x, const float* __restrict__ idx_f,
    const long long* __restrict__ idx_i, float4* __restrict__ outx,
    int idx64mode)
{
  int gid = blockIdx.x * 256 + threadIdx.x;   // one float4 per thread
  int chunk = gid & 31;                       // 32 float4 per 128-float row
  int bth = gid >> 5;                         // [0, 131072)
  int b = bth >> 16;                          // 65536 rows per batch
  int row = idx64mode ? (int)idx_i[bth] : (int)idx_f[bth];
  const float4* src = (const float4*)(x + ((size_t)(b * SS + row)) * EE);
  outx[gid] = src[chunk];
}

extern "C" void kernel_launch(void* const* d_in, const int* in_sizes, int n_in,
                              void* d_out, int out_size, void* d_ws, size_t ws_size,
                              hipStream_t stream)
{
  const float* x    = (const float*)d_in[0];
  const float* ct   = (const float*)d_in[1];
  const float* csrc = (const float*)d_in[2];
  float* out = (float*)d_out;

  // default: all outputs concatenated as f32 (idx cast). Defensive: if
  // out_size indicates an 8-byte idx region, store int64 there instead.
  int idx64mode = (out_size == (int)(XBS_N + 2 * IDX_N + CS_N)) ? 1 : 0;

  knn_select<<<512, 256, 0, stream>>>(ct, csrc, out, idx64mode);

  int nthreads = (int)(XBS_N / 4); // 4,194,304 float4 stores
  gather_x<<<nthreads / 256, 256, 0, stream>>>(
      x, out + XBS_N, (const long long*)(out + XBS_N), (float4*)out, idx64mode);
}

// Round 4
// 141.428 us; speedup vs baseline: 1.2252x; 1.2252x over previous
//
#include <hip/hip_runtime.h>

// knn gather: b=2, s=8192 sources, t=4096 targets, e=128, NH=16
#define NHH 16
#define KSEL 18   // extract 18 by (sq,idx), re-rank by (sqrt,idx), keep 16

constexpr int BB = 2, SS = 8192, TT = 4096, EE = 128;
constexpr long long XBS_N = (long long)BB * TT * NHH * EE; // 16777216
constexpr long long IDX_N = (long long)BB * TT * NHH;      // 131072
constexpr long long CS_N  = (long long)BB * 2 * TT * NHH;  // 262144

// LDS swizzle: phys = s ^ ((s>>7)&31). Bijective per 128-block; makes both
// stride-128 (per-lane segment scan) and stride-1 (cooperative rescan of one
// owner's segment) accesses land 2 lanes/bank (free per m136).
__device__ __forceinline__ int swz(int s) { return s ^ ((s >> 7) & 31); }

__device__ __forceinline__ unsigned long long wmin64(unsigned long long k) {
#pragma unroll
  for (int off = 32; off > 0; off >>= 1) {
    unsigned long long o = __shfl_xor(k, off, 64);
    k = (o < k) ? o : k;
  }
  return k;
}

// 512 threads = 8 waves, 2 targets/wave, 16 targets/block.
// 64KB LDS -> 2 blocks/CU -> 16 waves/CU (occupancy cap 50%, was 25%).
__global__ void __launch_bounds__(512, 4) knn_fused(
    const float* __restrict__ x, const float* __restrict__ ct,
    const float* __restrict__ csrc, float* __restrict__ out, int idx64mode)
{
  __shared__ float lc1[SS];
  __shared__ float lc2[SS];

  const int b = blockIdx.x >> 8;            // 512 blocks: 0..255 -> batch 0
  const float* c1g = csrc + (size_t)b * 2 * SS;
  const float* c2g = c1g + SS;
  for (int k = threadIdx.x; k < SS; k += 512) {
    lc1[swz(k)] = c1g[k];
    lc2[swz(k)] = c2g[k];
  }
  __syncthreads();

  const int lane = threadIdx.x & 63;
  const int wave = threadIdx.x >> 6;
  const int tbase = ((blockIdx.x & 255) << 4) + (wave << 1); // 2 targets/wave

  float tx[2], ty[2];
#pragma unroll
  for (int j = 0; j < 2; ++j) {
    tx[j] = ct[(size_t)b * 2 * TT + tbase + j];
    ty[j] = ct[(size_t)b * 2 * TT + TT + tbase + j];
  }

  // ---- scan: each lane owns sources [128*lane, 128*lane+128), tracks min key
  unsigned long long cur[2] = {~0ull, ~0ull};
  const int base = lane << 7;
  const int xr = lane & 31;
#pragma unroll 4
  for (int i = 0; i < 128; ++i) {
    float sx = lc1[base + (i ^ xr)];
    float sy = lc2[base + (i ^ xr)];
    int s = base + i;
#pragma unroll
    for (int j = 0; j < 2; ++j) {
      // exact rounding to match XLA: separate rn mul/mul/add, no fma
      float dx = __fsub_rn(tx[j], sx);
      float dy = __fsub_rn(ty[j], sy);
      float sq = __fadd_rn(__fmul_rn(dx, dx), __fmul_rn(dy, dy));
      unsigned long long key =
          ((unsigned long long)__float_as_uint(sq) << 13) | (unsigned)s;
      if (key < cur[j]) cur[j] = key;
    }
  }

#pragma unroll
  for (int j = 0; j < 2; ++j) {
    unsigned long long curj = cur[j];
    unsigned long long ext = ~0ull;    // lane e holds e-th extracted key
    for (int e = 0; e < KSEL; ++e) {
      unsigned long long kmin = wmin64(curj);
      if (lane == e) ext = kmin;
      int widx  = (int)(kmin & 8191u);
      int owner = widx >> 7;
      // cooperative rescan of owner's 128-candidate segment for min key > kmin
      int ob = owner << 7;
      int oxr = owner & 31;
      unsigned long long r = ~0ull;
#pragma unroll
      for (int h = 0; h < 2; ++h) {
        int ii = lane + (h << 6);
        float sx = lc1[ob + (ii ^ oxr)];
        float sy = lc2[ob + (ii ^ oxr)];
        float dx = __fsub_rn(tx[j], sx);
        float dy = __fsub_rn(ty[j], sy);
        float sq = __fadd_rn(__fmul_rn(dx, dx), __fmul_rn(dy, dy));
        unsigned long long key =
            ((unsigned long long)__float_as_uint(sq) << 13) | (unsigned)(ob + ii);
        if (key > kmin && key < r) r = key;
      }
      unsigned long long nm = wmin64(r);
      if (lane == owner) curj = nm;
    }

    // ---- re-rank the 18 by (sqrt(sq), idx) to reproduce stable argsort on d
    unsigned long long nk = ~0ull;
    int sidx = 0;
    if (lane < KSEL) {
      float sq = __uint_as_float((unsigned)(ext >> 13));
      sidx = (int)(ext & 8191u);
      float d = __fsqrt_rn(sq);  // correctly-rounded f32 sqrt (matches XLA)
      nk = ((unsigned long long)__float_as_uint(d) << 13) | (unsigned)sidx;
    }
    int rank = 0;
#pragma unroll
    for (int e = 0; e < KSEL; ++e) {
      unsigned long long o = __shfl(nk, e, 64);
      if (o < nk) ++rank;
    }
    int my_rank = (lane < KSEL) ? rank : 999;
    const int t = tbase + j;

    if (my_rank < NHH) {
      long long ibase = XBS_N;
      if (idx64mode) {
        ((long long*)(out + ibase))[(size_t)b * TT * NHH + t * NHH + my_rank] =
            (long long)sidx;
      } else {
        out[ibase + (size_t)b * TT * NHH + t * NHH + my_rank] = (float)sidx;
      }
      long long cbase = XBS_N + (idx64mode ? 2 * IDX_N : IDX_N);
      float sx = lc1[swz(sidx)];
      float sy = lc2[swz(sidx)];
      out[cbase + (size_t)b * 2 * TT * NHH + t * NHH + my_rank] =
          __fsub_rn(tx[j], sx);
      out[cbase + (size_t)b * 2 * TT * NHH + TT * NHH + t * NHH + my_rank] =
          __fsub_rn(ty[j], sy);
    }

    // ---- fused x gather: copy the 16 selected rows (2 rows per step,
    // lanes 0-31 handle rank h2, lanes 32-63 rank h2+1; 1 float4/lane)
#pragma unroll
    for (int h2 = 0; h2 < NHH; h2 += 2) {
      unsigned long long m0 = __ballot(my_rank == h2);
      unsigned long long m1 = __ballot(my_rank == h2 + 1);
      int s0 = __shfl(sidx, __ffsll(m0) - 1, 64);
      int s1 = __shfl(sidx, __ffsll(m1) - 1, 64);
      int row = (lane < 32) ? s0 : s1;
      int h = h2 + (lane >> 5);
      const float4* src = (const float4*)(x + ((size_t)(b * SS + row)) * EE);
      float4 v = src[lane & 31];
      ((float4*)out)[((size_t)((b * TT + t) * NHH + h) << 5) + (lane & 31)] = v;
    }
  }
}

extern "C" void kernel_launch(void* const* d_in, const int* in_sizes, int n_in,
                              void* d_out, int out_size, void* d_ws, size_t ws_size,
                              hipStream_t stream)
{
  const float* x    = (const float*)d_in[0];
  const float* ct   = (const float*)d_in[1];
  const float* csrc = (const float*)d_in[2];
  float* out = (float*)d_out;

  // default: all outputs concatenated as f32 (idx cast). Defensive: if
  // out_size indicates an 8-byte idx region, store int64 there instead.
  int idx64mode = (out_size == (int)(XBS_N + 2 * IDX_N + CS_N)) ? 1 : 0;

  knn_fused<<<512, 512, 0, stream>>>(x, ct, csrc, out, idx64mode);
}

// Round 6
// 125.695 us; speedup vs baseline: 1.3785x; 1.1252x over previous
//
#include <hip/hip_runtime.h>

// knn gather: b=2, s=8192 sources, t=4096 targets, e=128, NH=16
#define NHH 16
#define KSEL 18   // extract 18 by (sq,idx), re-rank by (sqrt,idx), keep 16

constexpr int BB = 2, SS = 8192, TT = 4096, EE = 128;
constexpr long long XBS_N = (long long)BB * TT * NHH * EE; // 16777216
constexpr long long IDX_N = (long long)BB * TT * NHH;      // 131072
constexpr long long CS_N  = (long long)BB * 2 * TT * NHH;  // 262144

#define FINF __uint_as_float(0x7f800000u)

// LDS swizzle: phys = s ^ ((s>>7)&31). Bijective per 128-block; stride-128
// per-lane scan and stride-1 cooperative rescan both land 2 lanes/bank (free).
__device__ __forceinline__ int swz(int s) { return s ^ ((s >> 7) & 31); }

__device__ __forceinline__ float wminf(float v) {
#pragma unroll
  for (int off = 32; off > 0; off >>= 1) v = fminf(v, __shfl_xor(v, off, 64));
  return v;
}

// min index among lanes whose val == minv (lex tiebreak; rare path = butterfly)
__device__ __forceinline__ int resolve_idx(float minv, float myv, int myidx) {
  unsigned long long m = __ballot(myv == minv);
  if (__popcll(m) == 1) return __shfl(myidx, (int)__ffsll(m) - 1, 64);
  int t = (myv == minv) ? myidx : 0x7fffffff;
#pragma unroll
  for (int off = 32; off > 0; off >>= 1) t = min(t, __shfl_xor(t, off, 64));
  return t;
}

// 1024 threads = 16 waves, 1 target/wave, 16 targets/block, 512 blocks.
// 64KB LDS -> 2 blocks/CU -> 32 waves/CU (100% occupancy cap).
__global__ void __launch_bounds__(1024, 8) knn_fused(
    const float* __restrict__ x, const float* __restrict__ ct,
    const float* __restrict__ csrc, float* __restrict__ out, int idx64mode)
{
  __shared__ float lc1[SS];
  __shared__ float lc2[SS];

  const int b = blockIdx.x >> 8;            // 512 blocks: 0..255 -> batch 0
  const float* c1g = csrc + (size_t)b * 2 * SS;
  const float* c2g = c1g + SS;
  for (int k = threadIdx.x; k < SS; k += 1024) {
    lc1[swz(k)] = c1g[k];
    lc2[swz(k)] = c2g[k];
  }
  __syncthreads();

  const int lane = threadIdx.x & 63;
  const int wave = threadIdx.x >> 6;
  const int t = ((blockIdx.x & 255) << 4) + wave;   // 1 target/wave

  const float tx = ct[(size_t)b * 2 * TT + t];
  const float ty = ct[(size_t)b * 2 * TT + TT + t];

  // ---- scan: each lane owns sources [128*lane, 128*lane+128),
  // keeps its top-2 by lex (sq, idx)
  float c0s = FINF, c1s = FINF;
  int c0i = 0, c1i = 0;
  const int base = lane << 7;
  const int xr = lane & 31;
#pragma unroll 4
  for (int i = 0; i < 128; ++i) {
    float sx = lc1[base + (i ^ xr)];
    float sy = lc2[base + (i ^ xr)];
    int s = base + i;
    // exact rounding to match XLA: separate rn mul/mul/add, no fma
    float dx = __fsub_rn(tx, sx);
    float dy = __fsub_rn(ty, sy);
    float sq = __fadd_rn(__fmul_rn(dx, dx), __fmul_rn(dy, dy));
    bool lt0 = (sq < c0s) || (sq == c0s && s < c0i);
    bool lt1 = (sq < c1s) || (sq == c1s && s < c1i);
    if (lt0) { c1s = c0s; c1i = c0i; c0s = sq; c0i = s; }
    else if (lt1) { c1s = sq; c1i = s; }
  }

  // ---- extraction: 18 rounds; common round = one f32 wave-min + owner pop.
  // Segment rescan (refill) only when a lane's both candidates are consumed.
  float esq = FINF; int eix = 0;   // lane e holds e-th extracted key
  for (int e = 0; e < KSEL; ++e) {
    float ms = wminf(c0s);
    int mi = resolve_idx(ms, c0s, c0i);
    if (lane == e) { esq = ms; eix = mi; }
    int owner = mi >> 7;
    if (lane == owner) { c0s = c1s; c0i = c1i; c1s = FINF; c1i = 0; }
    unsigned long long nb = __ballot(c0s == FINF);
    if (nb) {
      // refill owner's c0: min key strictly > (ms, mi) in owner's segment.
      // (ms,mi) is provably the last key extracted from this segment.
      int ob = owner << 7, oxr = owner & 31;
      float bs = FINF; int bi = 0;
#pragma unroll
      for (int h = 0; h < 2; ++h) {
        int ii = lane + (h << 6);
        int s = ob + ii;
        float sx = lc1[ob + (ii ^ oxr)];
        float sy = lc2[ob + (ii ^ oxr)];
        float dx = __fsub_rn(tx, sx);
        float dy = __fsub_rn(ty, sy);
        float sq = __fadd_rn(__fmul_rn(dx, dx), __fmul_rn(dy, dy));
        bool q = (sq > ms) || (sq == ms && s > mi);
        bool better = q && ((sq < bs) || (sq == bs && s < bi));
        if (better) { bs = sq; bi = s; }
      }
      float ms2 = wminf(bs);
      int mi2 = resolve_idx(ms2, bs, bi);
      if (lane == owner) { c0s = ms2; c0i = mi2; }
    }
  }

  // ---- re-rank the 18 by (sqrt(sq), idx) to reproduce stable argsort on d
  unsigned long long nk = ~0ull;
  if (lane < KSEL) {
    float d = __fsqrt_rn(esq);  // correctly-rounded f32 sqrt (matches XLA)
    nk = ((unsigned long long)__float_as_uint(d) << 13) | (unsigned)eix;
  }
  int rank = 0;
#pragma unroll
  for (int e = 0; e < KSEL; ++e) {
    unsigned long long o = __shfl(nk, e, 64);
    if (o < nk) ++rank;
  }
  const int my_rank = (lane < KSEL) ? rank : 999;
  const int sidx = eix;

  if (my_rank < NHH) {
    long long ibase = XBS_N;
    if (idx64mode) {
      ((long long*)(out + ibase))[(size_t)b * TT * NHH + t * NHH + my_rank] =
          (long long)sidx;
    } else {
      out[ibase + (size_t)b * TT * NHH + t * NHH + my_rank] = (float)sidx;
    }
    long long cbase = XBS_N + (idx64mode ? 2 * IDX_N : IDX_N);
    float sx = lc1[swz(sidx)];
    float sy = lc2[swz(sidx)];
    out[cbase + (size_t)b * 2 * TT * NHH + t * NHH + my_rank] =
        __fsub_rn(tx, sx);
    out[cbase + (size_t)b * 2 * TT * NHH + TT * NHH + t * NHH + my_rank] =
        __fsub_rn(ty, sy);
  }

  // ---- fused x gather: copy the 16 selected rows (2 rows per step,
  // lanes 0-31 handle rank h2, lanes 32-63 rank h2+1; 1 float4/lane)
#pragma unroll
  for (int h2 = 0; h2 < NHH; h2 += 2) {
    unsigned long long m0 = __ballot(my_rank == h2);
    unsigned long long m1 = __ballot(my_rank == h2 + 1);
    int s0 = __shfl(sidx, (int)__ffsll(m0) - 1, 64);
    int s1 = __shfl(sidx, (int)__ffsll(m1) - 1, 64);
    int row = (lane < 32) ? s0 : s1;
    int h = h2 + (lane >> 5);
    const float4* src = (const float4*)(x + ((size_t)(b * SS + row)) * EE);
    float4 v = src[lane & 31];
    ((float4*)out)[((size_t)((b * TT + t) * NHH + h) << 5) + (lane & 31)] = v;
  }
}

extern "C" void kernel_launch(void* const* d_in, const int* in_sizes, int n_in,
                              void* d_out, int out_size, void* d_ws, size_t ws_size,
                              hipStream_t stream)
{
  const float* x    = (const float*)d_in[0];
  const float* ct   = (const float*)d_in[1];
  const float* csrc = (const float*)d_in[2];
  float* out = (float*)d_out;

  // default: all outputs concatenated as f32 (idx cast). Defensive: if
  // out_size indicates an 8-byte idx region, store int64 there instead.
  int idx64mode = (out_size == (int)(XBS_N + 2 * IDX_N + CS_N)) ? 1 : 0;

  knn_fused<<<512, 1024, 0, stream>>>(x, ct, csrc, out, idx64mode);
}